// Round 4
// baseline (245.306 us; speedup 1.0000x reference)
//
#include <hip/hip_runtime.h>
#include <hip/hip_bf16.h>

typedef __bf16 bf16;
typedef __attribute__((ext_vector_type(8))) __bf16 bf16x8;
typedef __attribute__((ext_vector_type(4))) __bf16 bf16x4;
typedef __attribute__((ext_vector_type(4))) float f32x4;

#define M_TOK 32768   // B*S = 8*4096
#define D_    512
#define N_QKV 1536
#define BK    64
#define SCALE_ 0.125f

#define AS1 __attribute__((address_space(1)))
#define AS3 __attribute__((address_space(3)))

// ---------------- fp32 -> bf16 convert (vectorized) ----------------
__global__ __launch_bounds__(256) void cvt_bf16(const float* __restrict__ in,
                                                bf16* __restrict__ out, int n4) {
  int i = blockIdx.x * 256 + threadIdx.x;
  if (i >= n4) return;
  f32x4 v = ((const f32x4*)in)[i];
  bf16x4 o;
  o[0] = (bf16)v[0]; o[1] = (bf16)v[1]; o[2] = (bf16)v[2]; o[3] = (bf16)v[3];
  ((bf16x4*)out)[i] = o;
}

// ---------------- transpose+convert: fp32 in [K][N] -> bf16 out [N][K] ----------------
// PERM=1: head-major + qkv-interleaved column permutation for W_qkv:
//   orig col n = qkv*512 + h*64 + c  ->  out row h*192 + (c>>5)*96 + qkv*32 + (c&31)
// per head: [q0..31, k0..31, v0..31, q32..63, k32..63, v32..63]
template <int PERM>
__global__ __launch_bounds__(256) void transpose_cvt(const float* __restrict__ in,
                                                     bf16* __restrict__ out,
                                                     int K, int N) {
  __shared__ float tile[32][33];
  int n0 = blockIdx.x * 32, k0 = blockIdx.y * 32;
  int tx = threadIdx.x, ty = threadIdx.y;
  for (int i = 0; i < 32; i += 8)
    tile[ty + i][tx] = in[(size_t)(k0 + ty + i) * N + n0 + tx];
  __syncthreads();
  for (int i = 0; i < 32; i += 8) {
    int n = n0 + ty + i;
    int np = n;
    if (PERM) {
      int qkv = n >> 9, h = (n & 511) >> 6, c = n & 63;
      np = h * 192 + (c >> 5) * 96 + qkv * 32 + (c & 31);
    }
    out[(size_t)np * K + k0 + tx] = (bf16)tile[tx][ty + i];
  }
}

// ---------------- fused GEMM1 + per-head softmax (8-phase, template-faithful) ----
// Block 256 rows x 192 cols (one head), 512 threads = 8 waves (4 wrow x 2 wcol),
// wave tile 64x96, acc[4][6].
// LDS: sA triple-buffered (A staged 2 K-tiles ahead, HBM latency), sB double-
// buffered (L2-resident W, 1 tile ahead). 144 KB, 1 block/CU (2 waves/SIMD).
// Per K-tile, 4 phases. Template-faithful internals (r3 post-mortem = m141
// order-pinning): NO sched_barrier, NO explicit lgkmcnt — compiler emits
// fine-grained lgkm waits for ds_read->MFMA. Dual s_barrier per phase:
//   [ds_read subtile][stage loads][barrier][setprio(1) 12xMFMA setprio(0)][barrier]
// Counted vmcnt(6) once per K-tile at phase 0 (drains exactly tile t's 7 loads,
// leaves B(t+1)x2..3 + A(t+2)x4 in flight). Never drain to 0 in the main loop.
__global__ __launch_bounds__(512, 2) void gemm_qkv_softmax(const bf16* __restrict__ A,
                                                           const bf16* __restrict__ Bt,
                                                           const float* __restrict__ bqkv,
                                                           bf16* __restrict__ O) {
  __shared__ __align__(16) bf16 sA[3][256 * BK];   // 3 x 32 KB
  __shared__ __align__(16) bf16 sB[2][192 * BK];   // 2 x 24 KB

  const int tid = threadIdx.x;
  const int w = tid >> 6;              // 0..7
  const int l = tid & 63;
  const int m0 = blockIdx.x * 256;
  const int h  = blockIdx.y;           // head 0..7
  const int n0 = h * 192;
  const int wrow = w >> 1, wcol = w & 1;

  f32x4 acc[4][6];
#pragma unroll
  for (int i = 0; i < 4; ++i)
#pragma unroll
    for (int j = 0; j < 6; ++j) {
      f32x4 z = {0.f, 0.f, 0.f, 0.f};
      acc[i][j] = z;
    }

  // staging lane map: one load covers 8 rows x 128B; lane l -> row l>>3,
  // LDS slot l&7 holds global chunk (l&7)^(l>>3)  (XOR swizzle, both sides)
  const int srow = l >> 3;
  const int schunk = ((l & 7) ^ (l >> 3)) * 8;

  const int fr = l & 15;
  const int fkc = l >> 4;              // 16B chunk within 64B K-half
  const int frs = fr & 7;

  const bf16* gA = A + (size_t)(m0 + w * 32 + srow) * D_ + schunk;
  const bf16* gB = Bt + (size_t)(n0 + w * 24 + srow) * D_ + schunk;

  auto stA = [&](int buf, int kt, int q) {   // A rows w*32 + q*8 (+srow)
    __builtin_amdgcn_global_load_lds((AS1 const void*)(gA + (size_t)(q * 8) * D_ + kt),
                                     (AS3 void*)&sA[buf][(w * 32 + q * 8) * BK], 16, 0, 0);
  };
  auto stB = [&](int buf, int kt, int q) {   // B rows w*24 + q*8 (+srow)
    __builtin_amdgcn_global_load_lds((AS1 const void*)(gB + (size_t)(q * 8) * D_ + kt),
                                     (AS3 void*)&sB[buf][(w * 24 + q * 8) * BK], 16, 0, 0);
  };

  bf16x8 af[4];
  auto loadA = [&](int buf, int kk) {
    const int sw = (((kk << 2) | fkc) ^ frs) * 8;
#pragma unroll
    for (int i = 0; i < 4; ++i)
      af[i] = *(const bf16x8*)&sA[buf][(wrow * 64 + i * 16 + fr) * BK + sw];
  };
  bf16x8 bfr[3];
  auto loadB3 = [&](int buf, int kk, int jh) {
    const int sw = (((kk << 2) | fkc) ^ frs) * 8;
#pragma unroll
    for (int j = 0; j < 3; ++j)
      bfr[j] = *(const bf16x8*)&sB[buf][(wcol * 96 + (jh * 3 + j) * 16 + fr) * BK + sw];
  };
  auto mfma12 = [&](int jh) {
    __builtin_amdgcn_s_setprio(1);
#pragma unroll
    for (int i = 0; i < 4; ++i)
#pragma unroll
      for (int j = 0; j < 3; ++j)
        acc[i][jh * 3 + j] =
            __builtin_amdgcn_mfma_f32_16x16x32_bf16(af[i], bfr[j], acc[i][jh * 3 + j], 0, 0, 0);
    __builtin_amdgcn_s_setprio(0);
  };

  // prologue: A(0), B(0), A(1) — queue order = consumption order
#pragma unroll
  for (int q = 0; q < 4; ++q) stA(0, 0, q);
#pragma unroll
  for (int q = 0; q < 3; ++q) stB(0, 0, q);
#pragma unroll
  for (int q = 0; q < 4; ++q) stA(1, BK, q);

  const int NT = D_ / BK;              // 8 K-tiles
#pragma unroll
  for (int t = 0; t < NT; ++t) {
    const int cA = t % 3;              // A buffer for tile t
    const int cB = t & 1;              // B buffer for tile t
    const int nA = (t + 2) % 3;        // A dest (t+2)
    const int nB = cB ^ 1;             // B dest (t+1)
    const int ktA = (t + 2) * BK;
    const int ktB = (t + 1) * BK;
    const bool pfA = (t < NT - 2);
    const bool pfB = (t < NT - 1);

    // ---- phase 0 : kk0, j 0..2 ----
    if (pfB) { stB(nB, ktB, 0); stB(nB, ktB, 1); }
    if (t < NT - 1)
      asm volatile("s_waitcnt vmcnt(6)" ::: "memory");   // tile t fully staged
    else
      asm volatile("s_waitcnt vmcnt(0)" ::: "memory");
    __builtin_amdgcn_s_barrier();      // tile t visible to all waves
    loadA(cA, 0);
    loadB3(cB, 0, 0);
    mfma12(0);                         // compiler inserts fine-grained lgkm waits
    __builtin_amdgcn_s_barrier();

    // ---- phase 1 : kk0, j 3..5 (af reused) ----
    loadB3(cB, 0, 1);
    if (pfB) stB(nB, ktB, 2);
    if (pfA) stA(nA, ktA, 0);
    __builtin_amdgcn_s_barrier();
    mfma12(1);
    __builtin_amdgcn_s_barrier();

    // ---- phase 2 : kk1, j 0..2 ----
    loadA(cA, 1);
    loadB3(cB, 1, 0);
    if (pfA) { stA(nA, ktA, 1); stA(nA, ktA, 2); }
    __builtin_amdgcn_s_barrier();
    mfma12(0);
    __builtin_amdgcn_s_barrier();

    // ---- phase 3 : kk1, j 3..5 ----
    loadB3(cB, 1, 1);
    if (pfA) stA(nA, ktA, 3);
    __builtin_amdgcn_s_barrier();
    mfma12(1);
    __builtin_amdgcn_s_barrier();
  }

  // ---- epilogue: softmax over head dim, split across the wcol pair ----
  float bq[2], bkk[2], bv[2];
#pragma unroll
  for (int jq = 0; jq < 2; ++jq) {
    int c = h * 64 + wcol * 32 + jq * 16 + fr;
    bq[jq]  = bqkv[c];
    bkk[jq] = bqkv[512 + c];
    bv[jq]  = bqkv[1024 + c];
  }

  float* xm = (float*)&sA[0][0];       // [2][256] partial max
  float* xs = xm + 512;                // [2][256] partial expsum
  const int rbase = (l >> 4) * 4;

  float mpart[4][4], spart[4][4];
#pragma unroll
  for (int i = 0; i < 4; ++i) {
#pragma unroll
    for (int r = 0; r < 4; ++r) {
      float s0 = (acc[i][0][r] + bq[0] - acc[i][2][r] - bkk[0]) * SCALE_;
      float s1 = (acc[i][1][r] + bq[1] - acc[i][3][r] - bkk[1]) * SCALE_;
      float mx = fmaxf(s0, s1);
#pragma unroll
      for (int off = 1; off < 16; off <<= 1) mx = fmaxf(mx, __shfl_xor(mx, off));
      float e0 = __expf(s0 - mx);
      float e1 = __expf(s1 - mx);
      acc[i][0][r] = e0;               // stash exp values in freed acc slots
      acc[i][1][r] = e1;
      float sm = e0 + e1;
#pragma unroll
      for (int off = 1; off < 16; off <<= 1) sm += __shfl_xor(sm, off);
      mpart[i][r] = mx;
      spart[i][r] = sm;
      if (fr == 0) {
        int row = wrow * 64 + i * 16 + rbase + r;
        xm[wcol * 256 + row] = mx;
        xs[wcol * 256 + row] = sm;
      }
    }
  }
  __syncthreads();

#pragma unroll
  for (int i = 0; i < 4; ++i) {
#pragma unroll
    for (int r = 0; r < 4; ++r) {
      int row = wrow * 64 + i * 16 + rbase + r;
      float mo = xm[(wcol ^ 1) * 256 + row];
      float so = xs[(wcol ^ 1) * 256 + row];
      float mx = mpart[i][r];
      float M  = fmaxf(mx, mo);
      float esc_self  = __expf(mx - M);
      float esc_other = __expf(mo - M);
      float total = spart[i][r] * esc_self + so * esc_other;
      float inv = esc_self / total;
      int m = m0 + row;
      float o0 = acc[i][0][r] * inv * (acc[i][4][r] + bv[0]);
      float o1 = acc[i][1][r] * inv * (acc[i][5][r] + bv[1]);
      O[(size_t)m * D_ + h * 64 + wcol * 32 + fr]      = (bf16)o0;
      O[(size_t)m * D_ + h * 64 + wcol * 32 + 16 + fr] = (bf16)o1;
    }
  }
}

// ---------------- GEMM2: out = resid + O * Wp^T + bias (fp32 out) ----------------
// Dbuf + counted-vmcnt pipeline. LDS 64 KB -> 2 blocks/CU.
__global__ __launch_bounds__(256, 2) void gemm_bt_f32(const bf16* __restrict__ A,
                                                      const bf16* __restrict__ Bt,
                                                      const float* __restrict__ bias,
                                                      const float* __restrict__ resid,
                                                      float* __restrict__ C,
                                                      int M, int N, int K) {
  __shared__ __align__(16) bf16 sA[2][128 * BK];
  __shared__ __align__(16) bf16 sB[2][128 * BK];

  const int tid = threadIdx.x;
  const int w = tid >> 6;
  const int l = tid & 63;
  const int m0 = blockIdx.x * 128;
  const int n0 = blockIdx.y * 128;
  const int wrow = w >> 1, wcol = w & 1;

  f32x4 acc[4][4];
#pragma unroll
  for (int i = 0; i < 4; ++i)
#pragma unroll
    for (int j = 0; j < 4; ++j) {
      f32x4 z = {0.f, 0.f, 0.f, 0.f};
      acc[i][j] = z;
    }

  const int srow = l >> 3;
  const int schunk = ((l & 7) ^ (l >> 3)) * 8;
  const int fr = l & 15;
  const int fkc = l >> 4;
  const int frs = fr & 7;

  const bf16* gA = A + (size_t)(m0 + w * 32 + srow) * K + schunk;
  const bf16* gB = Bt + (size_t)(n0 + w * 32 + srow) * K + schunk;

  auto stageA = [&](int buf, int kt) {
#pragma unroll
    for (int q = 0; q < 4; ++q)
      __builtin_amdgcn_global_load_lds((AS1 const void*)(gA + (size_t)(q * 8) * K + kt),
                                       (AS3 void*)&sA[buf][(w * 32 + q * 8) * BK], 16, 0, 0);
  };
  auto stageB = [&](int buf, int kt) {
#pragma unroll
    for (int q = 0; q < 4; ++q)
      __builtin_amdgcn_global_load_lds((AS1 const void*)(gB + (size_t)(q * 8) * K + kt),
                                       (AS3 void*)&sB[buf][(w * 32 + q * 8) * BK], 16, 0, 0);
  };

  auto compute = [&](int buf, int kk) {
    const int sw = (((kk << 2) | fkc) ^ frs) * 8;
    bf16x8 af[4], bfr[4];
#pragma unroll
    for (int i = 0; i < 4; ++i)
      af[i] = *(const bf16x8*)&sA[buf][(wrow * 64 + i * 16 + fr) * BK + sw];
#pragma unroll
    for (int j = 0; j < 4; ++j)
      bfr[j] = *(const bf16x8*)&sB[buf][(wcol * 64 + j * 16 + fr) * BK + sw];
    __builtin_amdgcn_s_setprio(1);
#pragma unroll
    for (int i = 0; i < 4; ++i)
#pragma unroll
      for (int j = 0; j < 4; ++j)
        acc[i][j] = __builtin_amdgcn_mfma_f32_16x16x32_bf16(af[i], bfr[j], acc[i][j], 0, 0, 0);
    __builtin_amdgcn_s_setprio(0);
  };

  stageA(0, 0);
  stageB(0, 0);

  const int nt = K / BK;
  for (int t = 0; t < nt - 1; ++t) {
    const int cur = t & 1;
    stageA(cur ^ 1, (t + 1) * BK);
    asm volatile("s_waitcnt vmcnt(4)" ::: "memory");   // tile t's 8 loads done
    __builtin_amdgcn_s_barrier();
    asm volatile("" ::: "memory");
    compute(cur, 0);
    stageB(cur ^ 1, (t + 1) * BK);
    compute(cur, 1);
    asm volatile("" ::: "memory");
    __builtin_amdgcn_s_barrier();
  }
  {
    const int cur = (nt - 1) & 1;
    asm volatile("s_waitcnt vmcnt(0)" ::: "memory");
    __builtin_amdgcn_s_barrier();
    asm volatile("" ::: "memory");
    compute(cur, 0);
    compute(cur, 1);
  }

  const int col = l & 15;
  const int rbase = (l >> 4) * 4;
#pragma unroll
  for (int j = 0; j < 4; ++j) {
    int n = n0 + wcol * 64 + j * 16 + col;
    float bv = bias[n];
#pragma unroll
    for (int i = 0; i < 4; ++i) {
#pragma unroll
      for (int r = 0; r < 4; ++r) {
        int m = m0 + wrow * 64 + i * 16 + rbase + r;
        C[(size_t)m * N + n] = acc[i][j][r] + bv + resid[(size_t)m * N + n];
      }
    }
  }
}

extern "C" void kernel_launch(void* const* d_in, const int* in_sizes, int n_in,
                              void* d_out, int out_size, void* d_ws, size_t ws_size,
                              hipStream_t stream) {
  const float* x     = (const float*)d_in[0];   // [32768, 512]
  const float* Wqkv  = (const float*)d_in[1];   // [512, 1536]
  const float* bqkv  = (const float*)d_in[2];   // [1536]
  const float* Wproj = (const float*)d_in[3];   // [512, 512]
  const float* bproj = (const float*)d_in[4];   // [512]
  float* out = (float*)d_out;

  // workspace (~69.2 MB)
  char* ws = (char*)d_ws;
  bf16* Wq_t = (bf16*)ws;                               // [1536,512] perm  1.57 MB
  bf16* Wp_t = (bf16*)(ws + (size_t)N_QKV * D_ * 2);    // [512,512]        0.52 MB
  char* p = ws + (size_t)N_QKV * D_ * 2 + (size_t)D_ * D_ * 2;
  bf16* Xb = (bf16*)p;                                  // [32768,512] bf16 33.6 MB
  bf16* O  = (bf16*)(p + (size_t)M_TOK * D_ * 2);       // [32768,512] bf16 33.6 MB

  transpose_cvt<1><<<dim3(N_QKV / 32, D_ / 32), dim3(32, 8), 0, stream>>>(Wqkv, Wq_t, D_, N_QKV);
  transpose_cvt<0><<<dim3(D_ / 32, D_ / 32), dim3(32, 8), 0, stream>>>(Wproj, Wp_t, D_, D_);

  cvt_bf16<<<(M_TOK * D_ / 4 + 255) / 256, 256, 0, stream>>>(x, Xb, M_TOK * D_ / 4);

  gemm_qkv_softmax<<<dim3(M_TOK / 256, 8), 512, 0, stream>>>(Xb, Wq_t, bqkv, O);

  gemm_bt_f32<<<dim3(M_TOK / 128, D_ / 128), 256, 0, stream>>>(
      O, Wp_t, bproj, x, out, M_TOK, D_, D_);
}

// Round 5
// 229.579 us; speedup vs baseline: 1.0685x; 1.0685x over previous
//
#include <hip/hip_runtime.h>
#include <hip/hip_bf16.h>

typedef __bf16 bf16;
typedef __attribute__((ext_vector_type(8))) __bf16 bf16x8;
typedef __attribute__((ext_vector_type(4))) __bf16 bf16x4;
typedef __attribute__((ext_vector_type(4))) float f32x4;

#define M_TOK 32768   // B*S = 8*4096
#define D_    512
#define N_QKV 1536
#define BK    64
#define SCALE_ 0.125f

#define AS1 __attribute__((address_space(1)))
#define AS3 __attribute__((address_space(3)))

// ---------------- merged weight transpose+convert (one launch) ----------------
// bx < 48: W_qkv [512,1536] -> Wq_t [1536(perm),512] bf16, head-major +
//   qkv-interleaved: col n = qkv*512+h*64+c -> row h*192 + (c>>5)*96 + qkv*32 + (c&31)
// bx >= 48: W_proj [512,512] -> Wp_t [512,512] bf16 (plain transpose)
__global__ __launch_bounds__(256) void transpose_cvt_all(const float* __restrict__ Wqkv,
                                                         const float* __restrict__ Wproj,
                                                         bf16* __restrict__ Wq_t,
                                                         bf16* __restrict__ Wp_t) {
  __shared__ float tile[32][33];
  const int bx = blockIdx.x;
  const float* in;
  bf16* out;
  int N, n0;
  bool perm;
  if (bx < 48) { in = Wqkv;  out = Wq_t; N = 1536; n0 = bx * 32;        perm = true;  }
  else         { in = Wproj; out = Wp_t; N = 512;  n0 = (bx - 48) * 32; perm = false; }
  const int k0 = blockIdx.y * 32;
  const int tx = threadIdx.x, ty = threadIdx.y;
  for (int i = 0; i < 32; i += 8)
    tile[ty + i][tx] = in[(size_t)(k0 + ty + i) * N + n0 + tx];
  __syncthreads();
  for (int i = 0; i < 32; i += 8) {
    int n = n0 + ty + i;
    int np = n;
    if (perm) {
      int qkv = n >> 9, h = (n & 511) >> 6, c = n & 63;
      np = h * 192 + (c >> 5) * 96 + qkv * 32 + (c & 31);
    }
    out[(size_t)np * D_ + k0 + tx] = (bf16)tile[tx][ty + i];
  }
}

// ---------------- fused GEMM1 + per-head softmax (r2 2-phase + fp32-A reg-staging) --
// A = x fp32 [M,512] read DIRECTLY (cvt pass eliminated). Bt [1536(perm)][512] bf16.
// Block = 128 rows x 192 cols (one head), 256 threads, 4 waves as 2M x 2N
// (wave tile 64x96, acc[4][6], j = q0,q1,k0,k1,v0,v1). LDS 80 KB dbuf, 2 blocks/CU.
// Per K-tile (2-phase, the shape's best-known structure; 8-phase regressed r3/r4):
//   top:    issue Areg(t+1) fp32->regs (8x dwordx4) + stageB(t+1) (6x gload_lds)
//           s_waitcnt vmcnt(14)   // tile t's B done; 14 newer loads stay in flight
//           barrier; compute kk0+kk1 (setprio-wrapped MFMA)
//   tail:   cvt Areg->bf16, swizzled ds_write into buf t+1 (T14: write-late, HBM
//           latency hid under compute); lgkmcnt(0); barrier.
// Swizzle invariant both paths: LDS[row][slot] = global[row][slot ^ (row&7)].
__global__ __launch_bounds__(256, 2) void gemm_qkv_softmax(const float* __restrict__ A,
                                                           const bf16* __restrict__ Bt,
                                                           const float* __restrict__ bqkv,
                                                           bf16* __restrict__ O) {
  __shared__ __align__(16) bf16 sA[2][128 * BK];   // 2 x 16 KB
  __shared__ __align__(16) bf16 sB[2][192 * BK];   // 2 x 24 KB

  const int tid = threadIdx.x;
  const int w = tid >> 6;
  const int l = tid & 63;
  const int m0 = blockIdx.x * 128;
  const int h  = blockIdx.y;           // head 0..7
  const int n0 = h * 192;
  const int wrow = w >> 1, wcol = w & 1;

  f32x4 acc[4][6];
#pragma unroll
  for (int i = 0; i < 4; ++i)
#pragma unroll
    for (int j = 0; j < 6; ++j) {
      f32x4 z = {0.f, 0.f, 0.f, 0.f};
      acc[i][j] = z;
    }

  // staging lane map: one unit covers 8 rows x 64 elems; lane l -> row l>>3.
  const int srow = l >> 3;
  const int schunk = ((l & 7) ^ srow) * 8;     // B path: pre-swizzled global chunk
  const int fr = l & 15;
  const int fkc = l >> 4;
  const int frs = fr & 7;

  // A: natural (coalesced) fp32 chunk l&7; swizzle applied on the ds_write side.
  const float* gA = A + (size_t)(m0 + w * 32 + srow) * D_ + (l & 7) * 8;
  const bf16*  gB = Bt + (size_t)(n0 + w * 48 + srow) * D_ + schunk;

  f32x4 areg[4][2];
  auto aregLoad = [&](int kt) {
#pragma unroll
    for (int q = 0; q < 4; ++q) {
      const float* gp = gA + (size_t)(q * 8) * D_ + kt;
      areg[q][0] = *(const f32x4*)gp;
      areg[q][1] = *(const f32x4*)(gp + 4);
    }
  };
  auto aWrite = [&](int buf) {
#pragma unroll
    for (int q = 0; q < 4; ++q) {
      bf16x8 v;
#pragma unroll
      for (int e = 0; e < 4; ++e) { v[e] = (bf16)areg[q][0][e]; v[4 + e] = (bf16)areg[q][1][e]; }
      *(bf16x8*)&sA[buf][(w * 32 + q * 8 + srow) * BK + ((l & 7) ^ srow) * 8] = v;
    }
  };
  auto stageB = [&](int buf, int kt) {
#pragma unroll
    for (int q = 0; q < 6; ++q)
      __builtin_amdgcn_global_load_lds((AS1 const void*)(gB + (size_t)(q * 8) * D_ + kt),
                                       (AS3 void*)&sB[buf][(w * 48 + q * 8) * BK], 16, 0, 0);
  };

  auto compute = [&](int buf, int kk) {
    const int sw = (((kk << 2) | fkc) ^ frs) * 8;
    bf16x8 af[4], bfr[6];
#pragma unroll
    for (int i = 0; i < 4; ++i)
      af[i] = *(const bf16x8*)&sA[buf][(wrow * 64 + i * 16 + fr) * BK + sw];
#pragma unroll
    for (int j = 0; j < 6; ++j)
      bfr[j] = *(const bf16x8*)&sB[buf][(wcol * 96 + j * 16 + fr) * BK + sw];
    __builtin_amdgcn_s_setprio(1);
#pragma unroll
    for (int i = 0; i < 4; ++i)
#pragma unroll
      for (int j = 0; j < 6; ++j)
        acc[i][j] = __builtin_amdgcn_mfma_f32_16x16x32_bf16(af[i], bfr[j], acc[i][j], 0, 0, 0);
    __builtin_amdgcn_s_setprio(0);
  };

  // prologue: A(0) regs + B(0) DMA; write A(0) to LDS (compiler waits aregs).
  aregLoad(0);
  stageB(0, 0);
  aWrite(0);
  asm volatile("s_waitcnt lgkmcnt(0)" ::: "memory");

  const int NT = D_ / BK;              // 8 K-tiles
  for (int t = 0; t < NT; ++t) {
    const int cur = t & 1;
    if (t < NT - 1) {
      aregLoad((t + 1) * BK);          // 8 fp32x4 loads, land during compute
      stageB(cur ^ 1, (t + 1) * BK);   // 6 gload_lds
      asm volatile("s_waitcnt vmcnt(14)" ::: "memory");  // tile t's B done
    } else {
      asm volatile("s_waitcnt vmcnt(0)" ::: "memory");
    }
    __builtin_amdgcn_s_barrier();      // tile t fully visible
    asm volatile("" ::: "memory");
    compute(cur, 0);
    compute(cur, 1);
    if (t < NT - 1) {
      aWrite(cur ^ 1);                 // cvt + swizzled ds_write (write-late)
      asm volatile("s_waitcnt lgkmcnt(0)" ::: "memory");
    }
    asm volatile("" ::: "memory");
    __builtin_amdgcn_s_barrier();
  }

  // ---- epilogue: softmax over head dim, split across the wcol pair ----
  float bq[2], bkk[2], bv[2];
#pragma unroll
  for (int jq = 0; jq < 2; ++jq) {
    int c = h * 64 + wcol * 32 + jq * 16 + fr;
    bq[jq]  = bqkv[c];
    bkk[jq] = bqkv[512 + c];
    bv[jq]  = bqkv[1024 + c];
  }

  float* xm = (float*)&sA[0][0];       // [2][128] partial max
  float* xs = xm + 256;                // [2][128] partial expsum
  const int rbase = (l >> 4) * 4;

  float mpart[4][4], spart[4][4];
#pragma unroll
  for (int i = 0; i < 4; ++i) {
#pragma unroll
    for (int r = 0; r < 4; ++r) {
      float s0 = (acc[i][0][r] + bq[0] - acc[i][2][r] - bkk[0]) * SCALE_;
      float s1 = (acc[i][1][r] + bq[1] - acc[i][3][r] - bkk[1]) * SCALE_;
      float mx = fmaxf(s0, s1);
#pragma unroll
      for (int off = 1; off < 16; off <<= 1) mx = fmaxf(mx, __shfl_xor(mx, off));
      float e0 = __expf(s0 - mx);
      float e1 = __expf(s1 - mx);
      acc[i][0][r] = e0;               // stash exp values in freed acc slots
      acc[i][1][r] = e1;
      float sm = e0 + e1;
#pragma unroll
      for (int off = 1; off < 16; off <<= 1) sm += __shfl_xor(sm, off);
      mpart[i][r] = mx;
      spart[i][r] = sm;
      if (fr == 0) {
        int row = wrow * 64 + i * 16 + rbase + r;
        xm[wcol * 128 + row] = mx;
        xs[wcol * 128 + row] = sm;
      }
    }
  }
  __syncthreads();

#pragma unroll
  for (int i = 0; i < 4; ++i) {
#pragma unroll
    for (int r = 0; r < 4; ++r) {
      int row = wrow * 64 + i * 16 + rbase + r;
      float mo = xm[(wcol ^ 1) * 128 + row];
      float so = xs[(wcol ^ 1) * 128 + row];
      float mx = mpart[i][r];
      float M  = fmaxf(mx, mo);
      float esc_self  = __expf(mx - M);
      float esc_other = __expf(mo - M);
      float total = spart[i][r] * esc_self + so * esc_other;
      float inv = esc_self / total;
      int m = m0 + row;
      float o0 = acc[i][0][r] * inv * (acc[i][4][r] + bv[0]);
      float o1 = acc[i][1][r] * inv * (acc[i][5][r] + bv[1]);
      O[(size_t)m * D_ + h * 64 + wcol * 32 + fr]      = (bf16)o0;
      O[(size_t)m * D_ + h * 64 + wcol * 32 + 16 + fr] = (bf16)o1;
    }
  }
}

// ---------------- GEMM2: out = resid + O * Wp^T + bias (fp32 out) ----------------
// Dbuf + counted-vmcnt pipeline. LDS 64 KB -> 2 blocks/CU.
__global__ __launch_bounds__(256, 2) void gemm_bt_f32(const bf16* __restrict__ A,
                                                      const bf16* __restrict__ Bt,
                                                      const float* __restrict__ bias,
                                                      const float* __restrict__ resid,
                                                      float* __restrict__ C,
                                                      int M, int N, int K) {
  __shared__ __align__(16) bf16 sA[2][128 * BK];
  __shared__ __align__(16) bf16 sB[2][128 * BK];

  const int tid = threadIdx.x;
  const int w = tid >> 6;
  const int l = tid & 63;
  const int m0 = blockIdx.x * 128;
  const int n0 = blockIdx.y * 128;
  const int wrow = w >> 1, wcol = w & 1;

  f32x4 acc[4][4];
#pragma unroll
  for (int i = 0; i < 4; ++i)
#pragma unroll
    for (int j = 0; j < 4; ++j) {
      f32x4 z = {0.f, 0.f, 0.f, 0.f};
      acc[i][j] = z;
    }

  const int srow = l >> 3;
  const int schunk = ((l & 7) ^ (l >> 3)) * 8;
  const int fr = l & 15;
  const int fkc = l >> 4;
  const int frs = fr & 7;

  const bf16* gA = A + (size_t)(m0 + w * 32 + srow) * K + schunk;
  const bf16* gB = Bt + (size_t)(n0 + w * 32 + srow) * K + schunk;

  auto stageA = [&](int buf, int kt) {
#pragma unroll
    for (int q = 0; q < 4; ++q)
      __builtin_amdgcn_global_load_lds((AS1 const void*)(gA + (size_t)(q * 8) * K + kt),
                                       (AS3 void*)&sA[buf][(w * 32 + q * 8) * BK], 16, 0, 0);
  };
  auto stageB = [&](int buf, int kt) {
#pragma unroll
    for (int q = 0; q < 4; ++q)
      __builtin_amdgcn_global_load_lds((AS1 const void*)(gB + (size_t)(q * 8) * K + kt),
                                       (AS3 void*)&sB[buf][(w * 32 + q * 8) * BK], 16, 0, 0);
  };

  auto compute = [&](int buf, int kk) {
    const int sw = (((kk << 2) | fkc) ^ frs) * 8;
    bf16x8 af[4], bfr[4];
#pragma unroll
    for (int i = 0; i < 4; ++i)
      af[i] = *(const bf16x8*)&sA[buf][(wrow * 64 + i * 16 + fr) * BK + sw];
#pragma unroll
    for (int j = 0; j < 4; ++j)
      bfr[j] = *(const bf16x8*)&sB[buf][(wcol * 64 + j * 16 + fr) * BK + sw];
    __builtin_amdgcn_s_setprio(1);
#pragma unroll
    for (int i = 0; i < 4; ++i)
#pragma unroll
      for (int j = 0; j < 4; ++j)
        acc[i][j] = __builtin_amdgcn_mfma_f32_16x16x32_bf16(af[i], bfr[j], acc[i][j], 0, 0, 0);
    __builtin_amdgcn_s_setprio(0);
  };

  stageA(0, 0);
  stageB(0, 0);

  const int nt = K / BK;
  for (int t = 0; t < nt - 1; ++t) {
    const int cur = t & 1;
    stageA(cur ^ 1, (t + 1) * BK);
    asm volatile("s_waitcnt vmcnt(4)" ::: "memory");   // tile t's 8 loads done
    __builtin_amdgcn_s_barrier();
    asm volatile("" ::: "memory");
    compute(cur, 0);
    stageB(cur ^ 1, (t + 1) * BK);
    compute(cur, 1);
    asm volatile("" ::: "memory");
    __builtin_amdgcn_s_barrier();
  }
  {
    const int cur = (nt - 1) & 1;
    asm volatile("s_waitcnt vmcnt(0)" ::: "memory");
    __builtin_amdgcn_s_barrier();
    asm volatile("" ::: "memory");
    compute(cur, 0);
    compute(cur, 1);
  }

  const int col = l & 15;
  const int rbase = (l >> 4) * 4;
#pragma unroll
  for (int j = 0; j < 4; ++j) {
    int n = n0 + wcol * 64 + j * 16 + col;
    float bv = bias[n];
#pragma unroll
    for (int i = 0; i < 4; ++i) {
#pragma unroll
      for (int r = 0; r < 4; ++r) {
        int m = m0 + wrow * 64 + i * 16 + rbase + r;
        C[(size_t)m * N + n] = acc[i][j][r] + bv + resid[(size_t)m * N + n];
      }
    }
  }
}

extern "C" void kernel_launch(void* const* d_in, const int* in_sizes, int n_in,
                              void* d_out, int out_size, void* d_ws, size_t ws_size,
                              hipStream_t stream) {
  const float* x     = (const float*)d_in[0];   // [32768, 512]
  const float* Wqkv  = (const float*)d_in[1];   // [512, 1536]
  const float* bqkv  = (const float*)d_in[2];   // [1536]
  const float* Wproj = (const float*)d_in[3];   // [512, 512]
  const float* bproj = (const float*)d_in[4];   // [512]
  float* out = (float*)d_out;

  // workspace (~35.7 MB): Xb eliminated (gemm1 reads x fp32 directly)
  char* ws = (char*)d_ws;
  bf16* Wq_t = (bf16*)ws;                               // [1536,512] perm  1.57 MB
  bf16* Wp_t = (bf16*)(ws + (size_t)N_QKV * D_ * 2);    // [512,512]        0.52 MB
  bf16* O    = (bf16*)(ws + (size_t)N_QKV * D_ * 2 + (size_t)D_ * D_ * 2);  // 33.6 MB

  transpose_cvt_all<<<dim3(64, 16), dim3(32, 8), 0, stream>>>(Wqkv, Wproj, Wq_t, Wp_t);

  gemm_qkv_softmax<<<dim3(M_TOK / 128, 8), 256, 0, stream>>>(x, Wq_t, bqkv, O);

  gemm_bt_f32<<<dim3(M_TOK / 128, D_ / 128), 256, 0, stream>>>(
      O, Wp_t, bproj, x, out, M_TOK, D_, D_);
}